// Round 8
// baseline (350.817 us; speedup 1.0000x reference)
//
#include <hip/hip_runtime.h>
#include <hip/hip_bf16.h>
#include <stdint.h>

#define NTOK 8192
#define XSTRIDE 259
#define LOG2E 1.4426950408889634f
#define DECC (-3.4712336270551023f)   /* -4 + log2(log2 e) */
#define KSPLIT 8
#define SPLEN (NTOK / KSPLIT)   /* 1024 */
#define BN 32
#define ITERS (SPLEN / BN)      /* 32 */

typedef __bf16 bf16x8 __attribute__((ext_vector_type(8)));
typedef float f32x4 __attribute__((ext_vector_type(4)));
typedef unsigned short u16;

union BF8 { u16 u[8]; bf16x8 v; };
union PB  { uint64_t d[2]; bf16x8 v; };

__device__ __forceinline__ u16 f2bf(float f) {
  uint32_t u = __float_as_uint(f);
  u += 0x7FFFu + ((u >> 16) & 1u);
  return (u16)(u >> 16);
}
__device__ __forceinline__ float bf2f(u16 h) {
  return __uint_as_float(((uint32_t)h) << 16);
}
__device__ __forceinline__ float exp2_hw(float x) {
  float r; asm("v_exp_f32 %0, %1" : "=v"(r) : "v"(x)); return r;
}
template<int CTRL>
__device__ __forceinline__ float dpp_rot(float x) {
  int i = __float_as_int(x);
  int y = __builtin_amdgcn_update_dpp(i, i, CTRL, 0xF, 0xF, false);
  return __int_as_float(y);
}
__device__ __forceinline__ float rowsum16(float x) {
  x += dpp_rot<0x121>(x);
  x += dpp_rot<0x122>(x);
  x += dpp_rot<0x124>(x);
  x += dpp_rot<0x128>(x);
  return x;
}
__device__ __forceinline__ f32x4 mfma16(bf16x8 a, bf16x8 b, f32x4 c) {
  return __builtin_amdgcn_mfma_f32_16x16x32_bf16(a, b, c, 0, 0, 0);
}
__device__ __forceinline__ void async16(const void* g, void* l) {
  __builtin_amdgcn_global_load_lds(
      (const __attribute__((address_space(1))) uint32_t*)g,
      (__attribute__((address_space(3))) uint32_t*)l, 16, 0, 0);
}

// ---------------------------------------------------------------------------
// Kernel 0: pq[row] = (px, py, pz, 0.5*|P|^2)
// ---------------------------------------------------------------------------
__global__ void pq_kernel(const float* __restrict__ X, float* __restrict__ pq) {
  int r = blockIdx.x * 256 + threadIdx.x;
  const float* xp = X + (size_t)r * XSTRIDE + 256;
  float x = xp[0], y = xp[1], z = xp[2];
  f32x4 o = { x, y, z, 0.5f * (x * x + y * y + z * z) };
  ((f32x4*)pq)[r] = o;
}

// ---------------------------------------------------------------------------
// Kernel 0b: W^T bf16 prep. Wt[o_global][k] = bf16(W[k][o]).
// ---------------------------------------------------------------------------
__global__ __launch_bounds__(256) void wprep_kernel(
    const float* __restrict__ WQ, const float* __restrict__ WK,
    const float* __restrict__ WV, u16* __restrict__ Wt) {
  const int o = blockIdx.x;          // 0..767
  const int which = o >> 8, oo = o & 255;
  const float* W = (which == 0) ? WQ : ((which == 1) ? WK : WV);
  const int k = threadIdx.x;
  Wt[(size_t)o * 256 + k] = f2bf(W[(size_t)k * 256 + oo]);
}

// ---------------------------------------------------------------------------
// Kernel 1: QKV projection.  grid (64 rowblocks, 12 col-chunks).
// ---------------------------------------------------------------------------
__global__ __launch_bounds__(256) void qkv_kernel(
    const float* __restrict__ X, const u16* __restrict__ Wt,
    const float* __restrict__ bQ, const float* __restrict__ bK,
    const float* __restrict__ bV,
    u16* __restrict__ Qb, u16* __restrict__ Kb, u16* __restrict__ Vt) {
  __shared__ u16 wt[64 * 256];
  const int tid = threadIdx.x;
  const int lane = tid & 63;
  const int wave = tid >> 6;
  const int l15 = lane & 15;
  const int q4 = lane >> 4;
  const int rb = blockIdx.x;
  const int ch = blockIdx.y;
  const int which = ch >> 2;
  const int c0 = (ch & 3) * 64;
  const float* bias = (which == 0) ? bQ : ((which == 1) ? bK : bV);

  bf16x8 xa[2][8];
#pragma unroll
  for (int mt = 0; mt < 2; ++mt) {
    const int row = rb * 128 + wave * 32 + mt * 16 + l15;
#pragma unroll
    for (int kc = 0; kc < 8; ++kc) {
      const float* xp = X + (size_t)row * XSTRIDE + kc * 32 + q4 * 8;
      BF8 u;
#pragma unroll
      for (int jj = 0; jj < 8; ++jj) u.u[jj] = f2bf(xp[jj]);
      xa[mt][kc] = u.v;
    }
  }
  {
    const u16* Wsrc = Wt + (size_t)(which * 256 + c0) * 256;
    const int rb0 = wave * 16;
#pragma unroll
    for (int i = 0; i < 8; ++i) {
      int r = rb0 + i * 2 + (lane >> 5);
      int c = (lane & 31) ^ (r & 7);
      async16(Wsrc + (size_t)r * 256 + c * 8, wt + (rb0 + i * 2) * 256);
    }
  }
  asm volatile("s_waitcnt vmcnt(0)" ::: "memory");
  __syncthreads();

  f32x4 acc[2][4];
#pragma unroll
  for (int mt = 0; mt < 2; ++mt)
#pragma unroll
    for (int nt = 0; nt < 4; ++nt) acc[mt][nt] = (f32x4){0.f, 0.f, 0.f, 0.f};

#pragma unroll
  for (int kc = 0; kc < 8; ++kc) {
#pragma unroll
    for (int nt = 0; nt < 4; ++nt) {
      bf16x8 wf = *(const bf16x8*)(wt + (nt * 16 + l15) * 256 +
                                   (((kc * 4 + q4) ^ (l15 & 7)) * 8));
#pragma unroll
      for (int mt = 0; mt < 2; ++mt)
        acc[mt][nt] = mfma16(xa[mt][kc], wf, acc[mt][nt]);
    }
  }
  float bc[4];
#pragma unroll
  for (int nt = 0; nt < 4; ++nt) bc[nt] = bias[c0 + nt * 16 + l15];

#pragma unroll
  for (int mt = 0; mt < 2; ++mt)
#pragma unroll
    for (int nt = 0; nt < 4; ++nt)
#pragma unroll
      for (int r = 0; r < 4; ++r) {
        float v = acc[mt][nt][r] + bc[nt];
        int grow = rb * 128 + wave * 32 + mt * 16 + q4 * 4 + r;
        int gc = c0 + nt * 16 + l15;
        if (which == 2)      Vt[(size_t)gc * NTOK + grow] = f2bf(v);
        else if (which == 1) Kb[(size_t)grow * 256 + gc] = f2bf(v);
        else                 Qb[(size_t)grow * 256 + gc] = f2bf(v);
      }
}

// ---------------------------------------------------------------------------
// Kernel 2: flash attention, occupancy-first.
//  2 blocks/CU (2 waves/SIMD): LDS 76 KB/block, regs capped by
//  __launch_bounds__(256,2). Cross-wave overlap hides MFMA/VALU/LDS serial-
//  ization that killed 1-wave/SIMD configs (MFMA blocks its wave; only other
//  waves fill the pipes — m114).
//  Q A-frags re-loaded from global EVERY iteration (frees 64 regs); loads
//  issued BEFORE the prefetch asyncs so the in-order vmcnt wait for Q does
//  not drain the prefetch. zf-trick blocks LICM from hoisting them.
//  K/V/pqk double-buffered, ONE barrier per iter; pbuf single (same-wave
//  program order + lgkmcnt fence).
// ---------------------------------------------------------------------------
__global__ __launch_bounds__(256, 2) void attn_kernel(
    const u16* __restrict__ Qb, const u16* __restrict__ Kb,
    const u16* __restrict__ Vt, const float* __restrict__ pq,
    u16* __restrict__ Op, float* __restrict__ ml) {
  __shared__ u16 kbuf[2][BN * 256];     // 16 KB x2
  __shared__ u16 vbuf[2][256 * BN];     // 16 KB x2
  __shared__ u16 pbuf[4][32 * 36];      // per-wave P, single buffer (9 KB)
  __shared__ float pqk[2][BN * 4];      // key-side pq, dbuf (1 KB)
  __shared__ float pqs[128][4];         // query-side pq (2 KB)

  const int tid = threadIdx.x;
  const int lane = tid & 63;
  const int wave = tid >> 6;
  const int l15 = lane & 15;
  const int q4 = lane >> 4;
  const int rb = blockIdx.x;
  const int sp = blockIdx.y;
  const int q0 = rb * 128;
  const int wrow = wave * 32;

  if (tid < 128) ((f32x4*)pqs)[tid] = ((const f32x4*)pq)[q0 + tid];

  int zf; asm volatile("s_mov_b32 %0, 0" : "=s"(zf));  // opaque 0

#define STAGE(T)                                                              \
  do {                                                                        \
    const int key0_ = sp * SPLEN + (T) * BN;                                  \
    const int b_ = (T) & 1;                                                   \
    if (wave < 2) {                                                           \
      const int rb0 = wave * 16;                                              \
      _Pragma("unroll")                                                       \
      for (int i = 0; i < 8; ++i) {                                           \
        int r = rb0 + i * 2 + (lane >> 5);                                    \
        int c = (lane & 31) ^ (r & 7);                                        \
        async16(Kb + (size_t)(key0_ + r) * 256 + c * 8,                       \
                &kbuf[b_][(rb0 + i * 2) * 256]);                              \
      }                                                                       \
    } else {                                                                  \
      const int fb0 = (wave - 2) * 128;                                       \
      _Pragma("unroll")                                                       \
      for (int i = 0; i < 8; ++i) {                                           \
        int f = fb0 + i * 16 + (lane >> 2);                                   \
        int c = (lane & 3) ^ (f & 3);                                         \
        async16(Vt + (size_t)f * NTOK + key0_ + c * 8,                        \
                &vbuf[b_][(fb0 + i * 16) * 32]);                              \
      }                                                                       \
      if (wave == 3 && lane < 32)                                             \
        async16(((const f32x4*)pq) + key0_ + lane, &pqk[b_][0]);              \
    }                                                                         \
  } while (0)

  f32x4 O[2][16];
#pragma unroll
  for (int mt = 0; mt < 2; ++mt)
#pragma unroll
    for (int ft = 0; ft < 16; ++ft) O[mt][ft] = (f32x4){0.f, 0.f, 0.f, 0.f};
  float lrow[8];
#pragma unroll
  for (int i = 0; i < 8; ++i) lrow[i] = 0.f;

  // prologue: stage tile 0
  STAGE(0);

#pragma unroll 1
  for (int it = 0; it < ITERS; ++it) {
    const int cur = it & 1;
    asm volatile("s_waitcnt vmcnt(0)" ::: "memory");
    __syncthreads();

    // ---- Q loads (oldest in vmcnt queue; re-loaded each iter, L2-hot) ----
    bf16x8 qa[2][8];
    {
      const u16* qit = Qb + (size_t)(zf * it);
#pragma unroll
      for (int mt = 0; mt < 2; ++mt)
#pragma unroll
        for (int kc = 0; kc < 8; ++kc)
          qa[mt][kc] = *(const bf16x8*)(qit +
              (size_t)(q0 + wrow + mt * 16 + l15) * 256 + kc * 32 + q4 * 8);
    }
    asm volatile("" ::: "memory");  // pin Q-load issue before prefetch asyncs

    // ---- prefetch tile it+1 (last iter: benign identical rewrite) ----
    const int nx = (it + 1 < ITERS) ? (it + 1) : (ITERS - 1);
    STAGE(nx);

    // ---- S = Q K^T ----
    f32x4 S[2][2];
#pragma unroll
    for (int mt = 0; mt < 2; ++mt)
#pragma unroll
      for (int nt = 0; nt < 2; ++nt) S[mt][nt] = (f32x4){0.f, 0.f, 0.f, 0.f};
#pragma unroll
    for (int kc = 0; kc < 8; ++kc) {
#pragma unroll
      for (int nt = 0; nt < 2; ++nt) {
        bf16x8 kf = *(const bf16x8*)(&kbuf[cur][(nt * 16 + l15) * 256 +
                                     (((kc * 4 + q4) ^ (l15 & 7)) * 8)]);
#pragma unroll
        for (int mt = 0; mt < 2; ++mt)
          S[mt][nt] = mfma16(qa[mt][kc], kf, S[mt][nt]);
      }
    }

    // ---- decay + exp (fixed reference; x in [-4,4] by construction) ----
    {
      f32x4 pk[2];
#pragma unroll
      for (int nt = 0; nt < 2; ++nt)
        pk[nt] = ((const f32x4*)pqk[cur])[nt * 16 + l15];
#pragma unroll
      for (int mt = 0; mt < 2; ++mt) {
#pragma unroll
        for (int r = 0; r < 4; ++r) {
          f32x4 pr = *(const f32x4*)pqs[wrow + mt * 16 + q4 * 4 + r];
          float lacc = 0.f;
#pragma unroll
          for (int nt = 0; nt < 2; ++nt) {
            float h = pr[3] + pk[nt][3];
            h = fmaf(-pr[0], pk[nt][0], h);
            h = fmaf(-pr[1], pk[nt][1], h);
            h = fmaf(-pr[2], pk[nt][2], h);
            h = fmaxf(h, 0.f);
            float dec = exp2_hw(fmaf(h, -LOG2E, DECC));
            float p = exp2_hw(S[mt][nt][r] * dec);
            S[mt][nt][r] = p;
            lacc += p;
          }
          lrow[mt * 4 + r] += lacc;
        }
      }
    }

    // ---- P tile (bf16) into per-wave pbuf ----
    asm volatile("" ::: "memory");
#pragma unroll
    for (int mt = 0; mt < 2; ++mt)
#pragma unroll
      for (int nt = 0; nt < 2; ++nt)
#pragma unroll
        for (int r = 0; r < 4; ++r)
          pbuf[wave][(mt * 16 + q4 * 4 + r) * 36 + nt * 16 + l15] =
              f2bf(S[mt][nt][r]);
    asm volatile("s_waitcnt lgkmcnt(0)" ::: "memory");
    asm volatile("" ::: "memory");

    // ---- O += P V ----
    {
      bf16x8 pa[2];
#pragma unroll
      for (int mt = 0; mt < 2; ++mt) {
        PB pb;
        const u16* pp = &pbuf[wave][(mt * 16 + l15) * 36 + q4 * 8];
        pb.d[0] = *(const uint64_t*)(pp);
        pb.d[1] = *(const uint64_t*)(pp + 4);
        pa[mt] = pb.v;
      }
#pragma unroll
      for (int ft = 0; ft < 16; ++ft) {
        bf16x8 vf = *(const bf16x8*)(&vbuf[cur][(ft * 16 + l15) * 32 +
                                     ((q4 ^ (l15 & 3)) * 8)]);
#pragma unroll
        for (int mt = 0; mt < 2; ++mt)
          O[mt][ft] = mfma16(pa[mt], vf, O[mt][ft]);
      }
    }
  }

  // ---- epilogue: cross-lane row sums, write partial O and l ----
#pragma unroll
  for (int i = 0; i < 8; ++i) lrow[i] = rowsum16(lrow[i]);

#pragma unroll
  for (int mt = 0; mt < 2; ++mt)
#pragma unroll
    for (int ft = 0; ft < 16; ++ft)
#pragma unroll
      for (int r = 0; r < 4; ++r) {
        int row = q0 + wrow + mt * 16 + q4 * 4 + r;
        Op[((size_t)sp * NTOK + row) * 256 + ft * 16 + l15] = f2bf(O[mt][ft][r]);
      }
  if (l15 == 0) {
#pragma unroll
    for (int mt = 0; mt < 2; ++mt)
#pragma unroll
      for (int r = 0; r < 4; ++r) {
        int row = q0 + wrow + mt * 16 + q4 * 4 + r;
        ml[sp * NTOK + row] = lrow[mt * 4 + r];
      }
  }
#undef STAGE
}

// ---------------------------------------------------------------------------
// Kernel 3: combine splits: H = (sum O_s) / (1 + sum l_s) + residual.
// ---------------------------------------------------------------------------
__global__ __launch_bounds__(256) void combine_kernel(
    const float* __restrict__ X, const u16* __restrict__ Op,
    const float* __restrict__ ml, float* __restrict__ out) {
  const int row = blockIdx.x;
  const int f = threadIdx.x;
  float den = 1.f, num = 0.f;
#pragma unroll
  for (int s = 0; s < KSPLIT; ++s) {
    den += ml[s * NTOK + row];
    num += bf2f(Op[((size_t)s * NTOK + row) * 256 + f]);
  }
  out[(size_t)row * 256 + f] = num / den + X[(size_t)row * XSTRIDE + f];
}

// ---------------------------------------------------------------------------
extern "C" void kernel_launch(void* const* d_in, const int* in_sizes, int n_in,
                              void* d_out, int out_size, void* d_ws, size_t ws_size,
                              hipStream_t stream) {
  (void)in_sizes; (void)n_in; (void)out_size; (void)ws_size;
  const float* X  = (const float*)d_in[0];
  const float* WQ = (const float*)d_in[1];
  const float* bQ = (const float*)d_in[2];
  const float* WK = (const float*)d_in[3];
  const float* bK = (const float*)d_in[4];
  const float* WV = (const float*)d_in[5];
  const float* bV = (const float*)d_in[6];
  float* out = (float*)d_out;
  char* ws = (char*)d_ws;

  // ws: Qb 4M | Kb 4M | Vt 4M | pq 128K | Wt 384K | Op 32M | ml 256K
  u16*   Qb = (u16*)(ws);
  u16*   Kb = (u16*)(ws + ((size_t)4 << 20));
  u16*   Vt = (u16*)(ws + ((size_t)8 << 20));
  float* pq = (float*)(ws + ((size_t)12 << 20));
  u16*   Wt = (u16*)(ws + ((size_t)12 << 20) + 131072);
  u16*   Op = (u16*)(ws + ((size_t)12 << 20) + 131072 + 393216);
  float* ml = (float*)(ws + ((size_t)12 << 20) + 131072 + 393216 +
                       (size_t)KSPLIT * NTOK * 256 * 2);

  pq_kernel<<<dim3(NTOK / 256), dim3(256), 0, stream>>>(X, pq);
  wprep_kernel<<<dim3(768), dim3(256), 0, stream>>>(WQ, WK, WV, Wt);
  qkv_kernel<<<dim3(64, 12), dim3(256), 0, stream>>>(X, Wt, bQ, bK, bV,
                                                     Qb, Kb, Vt);
  attn_kernel<<<dim3(64, KSPLIT), dim3(256), 0, stream>>>(Qb, Kb, Vt, pq, Op, ml);
  combine_kernel<<<dim3(NTOK), dim3(256), 0, stream>>>(X, Op, ml, out);
}

// Round 9
// 239.464 us; speedup vs baseline: 1.4650x; 1.4650x over previous
//
#include <hip/hip_runtime.h>
#include <hip/hip_bf16.h>
#include <stdint.h>

#define NTOK 8192
#define XSTRIDE 259
#define LOG2E 1.4426950408889634f
#define DECC (-3.4712336270551023f)   /* -4 + log2(log2 e) */
#define KSPLIT 4
#define SPLEN (NTOK / KSPLIT)   /* 2048 */
#define BN 32
#define ITERS (SPLEN / BN)      /* 64 */

typedef __bf16 bf16x8 __attribute__((ext_vector_type(8)));
typedef float f32x4 __attribute__((ext_vector_type(4)));
typedef unsigned short u16;

union BF8 { u16 u[8]; bf16x8 v; };
union PB  { uint64_t d[2]; bf16x8 v; };

__device__ __forceinline__ u16 f2bf(float f) {
  uint32_t u = __float_as_uint(f);
  u += 0x7FFFu + ((u >> 16) & 1u);
  return (u16)(u >> 16);
}
__device__ __forceinline__ float bf2f(u16 h) {
  return __uint_as_float(((uint32_t)h) << 16);
}
__device__ __forceinline__ float exp2_hw(float x) {
  float r; asm("v_exp_f32 %0, %1" : "=v"(r) : "v"(x)); return r;
}
template<int CTRL>
__device__ __forceinline__ float dpp_rot(float x) {
  int i = __float_as_int(x);
  int y = __builtin_amdgcn_update_dpp(i, i, CTRL, 0xF, 0xF, false);
  return __int_as_float(y);
}
__device__ __forceinline__ float rowsum16(float x) {
  x += dpp_rot<0x121>(x);
  x += dpp_rot<0x122>(x);
  x += dpp_rot<0x124>(x);
  x += dpp_rot<0x128>(x);
  return x;
}
__device__ __forceinline__ f32x4 mfma16(bf16x8 a, bf16x8 b, f32x4 c) {
  return __builtin_amdgcn_mfma_f32_16x16x32_bf16(a, b, c, 0, 0, 0);
}
__device__ __forceinline__ void async16(const void* g, void* l) {
  __builtin_amdgcn_global_load_lds(
      (const __attribute__((address_space(1))) uint32_t*)g,
      (__attribute__((address_space(3))) uint32_t*)l, 16, 0, 0);
}

// ---------------------------------------------------------------------------
// Kernel 0: pq[row] = (px, py, pz, 0.5*|P|^2)
// ---------------------------------------------------------------------------
__global__ void pq_kernel(const float* __restrict__ X, float* __restrict__ pq) {
  int r = blockIdx.x * 256 + threadIdx.x;
  const float* xp = X + (size_t)r * XSTRIDE + 256;
  float x = xp[0], y = xp[1], z = xp[2];
  f32x4 o = { x, y, z, 0.5f * (x * x + y * y + z * z) };
  ((f32x4*)pq)[r] = o;
}

// ---------------------------------------------------------------------------
// Kernel 0b: W^T bf16 prep. Wt[o_global][k] = bf16(W[k][o]).
// ---------------------------------------------------------------------------
__global__ __launch_bounds__(256) void wprep_kernel(
    const float* __restrict__ WQ, const float* __restrict__ WK,
    const float* __restrict__ WV, u16* __restrict__ Wt) {
  const int o = blockIdx.x;          // 0..767
  const int which = o >> 8, oo = o & 255;
  const float* W = (which == 0) ? WQ : ((which == 1) ? WK : WV);
  const int k = threadIdx.x;
  Wt[(size_t)o * 256 + k] = f2bf(W[(size_t)k * 256 + oo]);
}

// ---------------------------------------------------------------------------
// Kernel 1: QKV projection.  grid (64 rowblocks, 12 col-chunks).
// ---------------------------------------------------------------------------
__global__ __launch_bounds__(256) void qkv_kernel(
    const float* __restrict__ X, const u16* __restrict__ Wt,
    const float* __restrict__ bQ, const float* __restrict__ bK,
    const float* __restrict__ bV,
    u16* __restrict__ Qb, u16* __restrict__ Kb, u16* __restrict__ Vt) {
  __shared__ u16 wt[64 * 256];
  const int tid = threadIdx.x;
  const int lane = tid & 63;
  const int wave = tid >> 6;
  const int l15 = lane & 15;
  const int q4 = lane >> 4;
  const int rb = blockIdx.x;
  const int ch = blockIdx.y;
  const int which = ch >> 2;
  const int c0 = (ch & 3) * 64;
  const float* bias = (which == 0) ? bQ : ((which == 1) ? bK : bV);

  bf16x8 xa[2][8];
#pragma unroll
  for (int mt = 0; mt < 2; ++mt) {
    const int row = rb * 128 + wave * 32 + mt * 16 + l15;
#pragma unroll
    for (int kc = 0; kc < 8; ++kc) {
      const float* xp = X + (size_t)row * XSTRIDE + kc * 32 + q4 * 8;
      BF8 u;
#pragma unroll
      for (int jj = 0; jj < 8; ++jj) u.u[jj] = f2bf(xp[jj]);
      xa[mt][kc] = u.v;
    }
  }
  {
    const u16* Wsrc = Wt + (size_t)(which * 256 + c0) * 256;
    const int rb0 = wave * 16;
#pragma unroll
    for (int i = 0; i < 8; ++i) {
      int r = rb0 + i * 2 + (lane >> 5);
      int c = (lane & 31) ^ (r & 7);
      async16(Wsrc + (size_t)r * 256 + c * 8, wt + (rb0 + i * 2) * 256);
    }
  }
  asm volatile("s_waitcnt vmcnt(0)" ::: "memory");
  __syncthreads();

  f32x4 acc[2][4];
#pragma unroll
  for (int mt = 0; mt < 2; ++mt)
#pragma unroll
    for (int nt = 0; nt < 4; ++nt) acc[mt][nt] = (f32x4){0.f, 0.f, 0.f, 0.f};

#pragma unroll
  for (int kc = 0; kc < 8; ++kc) {
#pragma unroll
    for (int nt = 0; nt < 4; ++nt) {
      bf16x8 wf = *(const bf16x8*)(wt + (nt * 16 + l15) * 256 +
                                   (((kc * 4 + q4) ^ (l15 & 7)) * 8));
#pragma unroll
      for (int mt = 0; mt < 2; ++mt)
        acc[mt][nt] = mfma16(xa[mt][kc], wf, acc[mt][nt]);
    }
  }
  float bc[4];
#pragma unroll
  for (int nt = 0; nt < 4; ++nt) bc[nt] = bias[c0 + nt * 16 + l15];

#pragma unroll
  for (int mt = 0; mt < 2; ++mt)
#pragma unroll
    for (int nt = 0; nt < 4; ++nt)
#pragma unroll
      for (int r = 0; r < 4; ++r) {
        float v = acc[mt][nt][r] + bc[nt];
        int grow = rb * 128 + wave * 32 + mt * 16 + q4 * 4 + r;
        int gc = c0 + nt * 16 + l15;
        if (which == 2)      Vt[(size_t)gc * NTOK + grow] = f2bf(v);
        else if (which == 1) Kb[(size_t)grow * 256 + gc] = f2bf(v);
        else                 Qb[(size_t)grow * 256 + gc] = f2bf(v);
      }
}

// ---------------------------------------------------------------------------
// Kernel 2: flash attention — feature-split pairing for occupancy.
//  grid (64 rb, 4 sp, 2 fh) = 512 blocks = 2/CU (2 waves/SIMD).
//  Each block: full S = QK^T for its 128 rows (QK duplicated across the fh
//  pair — paid deliberately), PV/O for only 128 features -> O = 64 regs.
//  Q persistent (64 regs). Total regs ~210 < 256 -> 2 waves/SIMD, no spill,
//  ZERO in-loop vmem except prefetch. Cross-wave overlap (m114) now hides
//  the single-stream MFMA/VALU/LDS serialization that capped R5-R7.
//  LDS ~60 KB/block -> 2 blocks/CU. linear%8 = rb%8: fh-pair + all sp of a
//  rb share an XCD (K tiles L2-shared).
// ---------------------------------------------------------------------------
__global__ __launch_bounds__(256, 2) void attn_kernel(
    const u16* __restrict__ Qb, const u16* __restrict__ Kb,
    const u16* __restrict__ Vt, const float* __restrict__ pq,
    u16* __restrict__ Op, float* __restrict__ ml) {
  __shared__ u16 kbuf[2][BN * 256];     // 16 KB x2
  __shared__ u16 vbuf[2][128 * BN];     // 8 KB x2 (feature half)
  __shared__ u16 pbuf[4][32 * 36];      // per-wave P (9 KB)
  __shared__ float pqk[2][BN * 4];      // key-side pq, dbuf (1 KB)
  __shared__ float pqs[128][4];         // query-side pq (2 KB)

  const int tid = threadIdx.x;
  const int lane = tid & 63;
  const int wave = tid >> 6;
  const int l15 = lane & 15;
  const int q4 = lane >> 4;
  const int rb = blockIdx.x;
  const int sp = blockIdx.y;
  const int fh = blockIdx.z;
  const int q0 = rb * 128;
  const int wrow = wave * 32;

  if (tid < 128) ((f32x4*)pqs)[tid] = ((const f32x4*)pq)[q0 + tid];

#define STAGE(T)                                                              \
  do {                                                                        \
    const int key0_ = sp * SPLEN + (T) * BN;                                  \
    const int b_ = (T) & 1;                                                   \
    if (wave < 2) {                                                           \
      const int rb0 = wave * 16;                                              \
      _Pragma("unroll")                                                       \
      for (int i = 0; i < 8; ++i) {                                           \
        int r = rb0 + i * 2 + (lane >> 5);                                    \
        int c = (lane & 31) ^ (r & 7);                                        \
        async16(Kb + (size_t)(key0_ + r) * 256 + c * 8,                       \
                &kbuf[b_][(rb0 + i * 2) * 256]);                              \
      }                                                                       \
    } else {                                                                  \
      const int fb0 = (wave - 2) * 64;                                        \
      _Pragma("unroll")                                                       \
      for (int i = 0; i < 4; ++i) {                                           \
        int f = fb0 + i * 16 + (lane >> 2);                                   \
        int c = (lane & 3) ^ (f & 3);                                         \
        async16(Vt + (size_t)(fh * 128 + f) * NTOK + key0_ + c * 8,           \
                &vbuf[b_][(fb0 + i * 16) * 32]);                              \
      }                                                                       \
      if (wave == 3 && lane < 32)                                             \
        async16(((const f32x4*)pq) + key0_ + lane, &pqk[b_][0]);              \
    }                                                                         \
  } while (0)

  // ---- Q fragments: persistent in registers for the whole kernel ----
  bf16x8 qa[2][8];
#pragma unroll
  for (int mt = 0; mt < 2; ++mt)
#pragma unroll
    for (int kc = 0; kc < 8; ++kc)
      qa[mt][kc] = *(const bf16x8*)(Qb + (size_t)(q0 + wrow + mt * 16 + l15) * 256 +
                                    kc * 32 + q4 * 8);

  f32x4 O[2][8];
#pragma unroll
  for (int mt = 0; mt < 2; ++mt)
#pragma unroll
    for (int ft = 0; ft < 8; ++ft) O[mt][ft] = (f32x4){0.f, 0.f, 0.f, 0.f};
  float lrow[8];
#pragma unroll
  for (int i = 0; i < 8; ++i) lrow[i] = 0.f;

  STAGE(0);

#pragma unroll 1
  for (int it = 0; it < ITERS; ++it) {
    const int cur = it & 1;
    asm volatile("s_waitcnt vmcnt(0)" ::: "memory");
    __syncthreads();

    // prefetch tile it+1 (last iter: benign identical rewrite)
    const int nx = (it + 1 < ITERS) ? (it + 1) : (ITERS - 1);
    STAGE(nx);

    // ---- S = Q K^T (full 256-D, duplicated across the fh pair) ----
    f32x4 S[2][2];
#pragma unroll
    for (int mt = 0; mt < 2; ++mt)
#pragma unroll
      for (int nt = 0; nt < 2; ++nt) S[mt][nt] = (f32x4){0.f, 0.f, 0.f, 0.f};
#pragma unroll
    for (int kc = 0; kc < 8; ++kc) {
#pragma unroll
      for (int nt = 0; nt < 2; ++nt) {
        bf16x8 kf = *(const bf16x8*)(&kbuf[cur][(nt * 16 + l15) * 256 +
                                     (((kc * 4 + q4) ^ (l15 & 7)) * 8)]);
#pragma unroll
        for (int mt = 0; mt < 2; ++mt)
          S[mt][nt] = mfma16(qa[mt][kc], kf, S[mt][nt]);
      }
    }

    // ---- decay + exp (fixed reference; x in [-4,4] by construction) ----
    {
      f32x4 pk[2];
#pragma unroll
      for (int nt = 0; nt < 2; ++nt)
        pk[nt] = ((const f32x4*)pqk[cur])[nt * 16 + l15];
#pragma unroll
      for (int mt = 0; mt < 2; ++mt) {
#pragma unroll
        for (int r = 0; r < 4; ++r) {
          f32x4 pr = *(const f32x4*)pqs[wrow + mt * 16 + q4 * 4 + r];
          float lacc = 0.f;
#pragma unroll
          for (int nt = 0; nt < 2; ++nt) {
            float h = pr[3] + pk[nt][3];
            h = fmaf(-pr[0], pk[nt][0], h);
            h = fmaf(-pr[1], pk[nt][1], h);
            h = fmaf(-pr[2], pk[nt][2], h);
            h = fmaxf(h, 0.f);
            float dec = exp2_hw(fmaf(h, -LOG2E, DECC));
            float p = exp2_hw(S[mt][nt][r] * dec);
            S[mt][nt][r] = p;
            lacc += p;
          }
          lrow[mt * 4 + r] += lacc;
        }
      }
    }

    // ---- P tile (bf16) into per-wave pbuf ----
    asm volatile("" ::: "memory");
#pragma unroll
    for (int mt = 0; mt < 2; ++mt)
#pragma unroll
      for (int nt = 0; nt < 2; ++nt)
#pragma unroll
        for (int r = 0; r < 4; ++r)
          pbuf[wave][(mt * 16 + q4 * 4 + r) * 36 + nt * 16 + l15] =
              f2bf(S[mt][nt][r]);
    asm volatile("s_waitcnt lgkmcnt(0)" ::: "memory");
    asm volatile("" ::: "memory");

    // ---- O += P V (feature half only) ----
    {
      bf16x8 pa[2];
#pragma unroll
      for (int mt = 0; mt < 2; ++mt) {
        PB pb;
        const u16* pp = &pbuf[wave][(mt * 16 + l15) * 36 + q4 * 8];
        pb.d[0] = *(const uint64_t*)(pp);
        pb.d[1] = *(const uint64_t*)(pp + 4);
        pa[mt] = pb.v;
      }
#pragma unroll
      for (int ft = 0; ft < 8; ++ft) {
        bf16x8 vf = *(const bf16x8*)(&vbuf[cur][(ft * 16 + l15) * 32 +
                                     ((q4 ^ (l15 & 3)) * 8)]);
#pragma unroll
        for (int mt = 0; mt < 2; ++mt)
          O[mt][ft] = mfma16(pa[mt], vf, O[mt][ft]);
      }
    }
  }

  // ---- epilogue ----
#pragma unroll
  for (int i = 0; i < 8; ++i) lrow[i] = rowsum16(lrow[i]);

#pragma unroll
  for (int mt = 0; mt < 2; ++mt)
#pragma unroll
    for (int ft = 0; ft < 8; ++ft)
#pragma unroll
      for (int r = 0; r < 4; ++r) {
        int row = q0 + wrow + mt * 16 + q4 * 4 + r;
        int f = fh * 128 + ft * 16 + l15;
        Op[((size_t)sp * NTOK + row) * 256 + f] = f2bf(O[mt][ft][r]);
      }
  if (fh == 0 && l15 == 0) {
#pragma unroll
    for (int mt = 0; mt < 2; ++mt)
#pragma unroll
      for (int r = 0; r < 4; ++r) {
        int row = q0 + wrow + mt * 16 + q4 * 4 + r;
        ml[sp * NTOK + row] = lrow[mt * 4 + r];
      }
  }
#undef STAGE
}

// ---------------------------------------------------------------------------
// Kernel 3: combine splits: H = (sum O_s) / (1 + sum l_s) + residual.
// ---------------------------------------------------------------------------
__global__ __launch_bounds__(256) void combine_kernel(
    const float* __restrict__ X, const u16* __restrict__ Op,
    const float* __restrict__ ml, float* __restrict__ out) {
  const int row = blockIdx.x;
  const int f = threadIdx.x;
  float den = 1.f, num = 0.f;
#pragma unroll
  for (int s = 0; s < KSPLIT; ++s) {
    den += ml[s * NTOK + row];
    num += bf2f(Op[((size_t)s * NTOK + row) * 256 + f]);
  }
  out[(size_t)row * 256 + f] = num / den + X[(size_t)row * XSTRIDE + f];
}

// ---------------------------------------------------------------------------
extern "C" void kernel_launch(void* const* d_in, const int* in_sizes, int n_in,
                              void* d_out, int out_size, void* d_ws, size_t ws_size,
                              hipStream_t stream) {
  (void)in_sizes; (void)n_in; (void)out_size; (void)ws_size;
  const float* X  = (const float*)d_in[0];
  const float* WQ = (const float*)d_in[1];
  const float* bQ = (const float*)d_in[2];
  const float* WK = (const float*)d_in[3];
  const float* bK = (const float*)d_in[4];
  const float* WV = (const float*)d_in[5];
  const float* bV = (const float*)d_in[6];
  float* out = (float*)d_out;
  char* ws = (char*)d_ws;

  // ws: Qb 4M | Kb 4M | Vt 4M | pq 128K | Wt 384K | Op 16M | ml 128K
  u16*   Qb = (u16*)(ws);
  u16*   Kb = (u16*)(ws + ((size_t)4 << 20));
  u16*   Vt = (u16*)(ws + ((size_t)8 << 20));
  float* pq = (float*)(ws + ((size_t)12 << 20));
  u16*   Wt = (u16*)(ws + ((size_t)12 << 20) + 131072);
  u16*   Op = (u16*)(ws + ((size_t)12 << 20) + 131072 + 393216);
  float* ml = (float*)(ws + ((size_t)12 << 20) + 131072 + 393216 +
                       (size_t)KSPLIT * NTOK * 256 * 2);

  pq_kernel<<<dim3(NTOK / 256), dim3(256), 0, stream>>>(X, pq);
  wprep_kernel<<<dim3(768), dim3(256), 0, stream>>>(WQ, WK, WV, Wt);
  qkv_kernel<<<dim3(64, 12), dim3(256), 0, stream>>>(X, Wt, bQ, bK, bV,
                                                     Qb, Kb, Vt);
  attn_kernel<<<dim3(64, KSPLIT, 2), dim3(256), 0, stream>>>(Qb, Kb, Vt, pq,
                                                             Op, ml);
  combine_kernel<<<dim3(NTOK), dim3(256), 0, stream>>>(X, Op, ml, out);
}

// Round 10
// 200.138 us; speedup vs baseline: 1.7529x; 1.1965x over previous
//
#include <hip/hip_runtime.h>
#include <hip/hip_bf16.h>
#include <stdint.h>

#define NTOK 8192
#define XSTRIDE 259
#define LOG2E 1.4426950408889634f
#define DECC (-3.4712336270551023f)   /* -4 + log2(log2 e) */
#define KSPLIT 4
#define SPLEN (NTOK / KSPLIT)   /* 2048 */
#define BN 32
#define ITERS (SPLEN / BN)      /* 64 */

typedef __bf16 bf16x8 __attribute__((ext_vector_type(8)));
typedef float f32x4 __attribute__((ext_vector_type(4)));
typedef unsigned short u16;

union BF8 { u16 u[8]; bf16x8 v; };
union PB  { uint64_t d[2]; bf16x8 v; };

__device__ __forceinline__ u16 f2bf(float f) {
  uint32_t u = __float_as_uint(f);
  u += 0x7FFFu + ((u >> 16) & 1u);
  return (u16)(u >> 16);
}
__device__ __forceinline__ float bf2f(u16 h) {
  return __uint_as_float(((uint32_t)h) << 16);
}
__device__ __forceinline__ float exp2_hw(float x) {
  float r; asm("v_exp_f32 %0, %1" : "=v"(r) : "v"(x)); return r;
}
template<int CTRL>
__device__ __forceinline__ float dpp_rot(float x) {
  int i = __float_as_int(x);
  int y = __builtin_amdgcn_update_dpp(i, i, CTRL, 0xF, 0xF, false);
  return __int_as_float(y);
}
__device__ __forceinline__ float rowsum16(float x) {
  x += dpp_rot<0x121>(x);
  x += dpp_rot<0x122>(x);
  x += dpp_rot<0x124>(x);
  x += dpp_rot<0x128>(x);
  return x;
}
__device__ __forceinline__ f32x4 mfma16(bf16x8 a, bf16x8 b, f32x4 c) {
  return __builtin_amdgcn_mfma_f32_16x16x32_bf16(a, b, c, 0, 0, 0);
}
__device__ __forceinline__ void async16(const void* g, void* l) {
  __builtin_amdgcn_global_load_lds(
      (const __attribute__((address_space(1))) uint32_t*)g,
      (__attribute__((address_space(3))) uint32_t*)l, 16, 0, 0);
}

// ---------------------------------------------------------------------------
// Kernel 0: pq[row] = (px, py, pz, 0.5*|P|^2)
// ---------------------------------------------------------------------------
__global__ void pq_kernel(const float* __restrict__ X, float* __restrict__ pq) {
  int r = blockIdx.x * 256 + threadIdx.x;
  const float* xp = X + (size_t)r * XSTRIDE + 256;
  float x = xp[0], y = xp[1], z = xp[2];
  f32x4 o = { x, y, z, 0.5f * (x * x + y * y + z * z) };
  ((f32x4*)pq)[r] = o;
}

// ---------------------------------------------------------------------------
// Kernel 0b: W^T bf16 prep. Wt[o_global][k] = bf16(W[k][o]).
// ---------------------------------------------------------------------------
__global__ __launch_bounds__(256) void wprep_kernel(
    const float* __restrict__ WQ, const float* __restrict__ WK,
    const float* __restrict__ WV, u16* __restrict__ Wt) {
  const int o = blockIdx.x;          // 0..767
  const int which = o >> 8, oo = o & 255;
  const float* W = (which == 0) ? WQ : ((which == 1) ? WK : WV);
  const int k = threadIdx.x;
  Wt[(size_t)o * 256 + k] = f2bf(W[(size_t)k * 256 + oo]);
}

// ---------------------------------------------------------------------------
// Kernel 1: QKV projection.  grid (64 rowblocks, 12 col-chunks).
// ---------------------------------------------------------------------------
__global__ __launch_bounds__(256) void qkv_kernel(
    const float* __restrict__ X, const u16* __restrict__ Wt,
    const float* __restrict__ bQ, const float* __restrict__ bK,
    const float* __restrict__ bV,
    u16* __restrict__ Qb, u16* __restrict__ Kb, u16* __restrict__ Vt) {
  __shared__ u16 wt[64 * 256];
  const int tid = threadIdx.x;
  const int lane = tid & 63;
  const int wave = tid >> 6;
  const int l15 = lane & 15;
  const int q4 = lane >> 4;
  const int rb = blockIdx.x;
  const int ch = blockIdx.y;
  const int which = ch >> 2;
  const int c0 = (ch & 3) * 64;
  const float* bias = (which == 0) ? bQ : ((which == 1) ? bK : bV);

  bf16x8 xa[2][8];
#pragma unroll
  for (int mt = 0; mt < 2; ++mt) {
    const int row = rb * 128 + wave * 32 + mt * 16 + l15;
#pragma unroll
    for (int kc = 0; kc < 8; ++kc) {
      const float* xp = X + (size_t)row * XSTRIDE + kc * 32 + q4 * 8;
      BF8 u;
#pragma unroll
      for (int jj = 0; jj < 8; ++jj) u.u[jj] = f2bf(xp[jj]);
      xa[mt][kc] = u.v;
    }
  }
  {
    const u16* Wsrc = Wt + (size_t)(which * 256 + c0) * 256;
    const int rb0 = wave * 16;
#pragma unroll
    for (int i = 0; i < 8; ++i) {
      int r = rb0 + i * 2 + (lane >> 5);
      int c = (lane & 31) ^ (r & 7);
      async16(Wsrc + (size_t)r * 256 + c * 8, wt + (rb0 + i * 2) * 256);
    }
  }
  asm volatile("s_waitcnt vmcnt(0)" ::: "memory");
  __syncthreads();

  f32x4 acc[2][4];
#pragma unroll
  for (int mt = 0; mt < 2; ++mt)
#pragma unroll
    for (int nt = 0; nt < 4; ++nt) acc[mt][nt] = (f32x4){0.f, 0.f, 0.f, 0.f};

#pragma unroll
  for (int kc = 0; kc < 8; ++kc) {
#pragma unroll
    for (int nt = 0; nt < 4; ++nt) {
      bf16x8 wf = *(const bf16x8*)(wt + (nt * 16 + l15) * 256 +
                                   (((kc * 4 + q4) ^ (l15 & 7)) * 8));
#pragma unroll
      for (int mt = 0; mt < 2; ++mt)
        acc[mt][nt] = mfma16(xa[mt][kc], wf, acc[mt][nt]);
    }
  }
  float bc[4];
#pragma unroll
  for (int nt = 0; nt < 4; ++nt) bc[nt] = bias[c0 + nt * 16 + l15];

#pragma unroll
  for (int mt = 0; mt < 2; ++mt)
#pragma unroll
    for (int nt = 0; nt < 4; ++nt)
#pragma unroll
      for (int r = 0; r < 4; ++r) {
        float v = acc[mt][nt][r] + bc[nt];
        int grow = rb * 128 + wave * 32 + mt * 16 + q4 * 4 + r;
        int gc = c0 + nt * 16 + l15;
        if (which == 2)      Vt[(size_t)gc * NTOK + grow] = f2bf(v);
        else if (which == 1) Kb[(size_t)grow * 256 + gc] = f2bf(v);
        else                 Qb[(size_t)grow * 256 + gc] = f2bf(v);
      }
}

// ---------------------------------------------------------------------------
// Kernel 2: flash attention — M=16 rows/wave, NO duplicated work.
//  grid (128 rb, 4 sp) = 512 blocks = 2/CU (2 waves/SIMD, R9-proven).
//  Block = 64 Q-rows, FULL 256 features: O=64 regs, Q=32, S=8, pr=16 ->
//  ~170 regs total under the (256,2) cap, zero spill, zero duplication
//  (total MFMA back to 4.19M minimum, softmax VALU computed once/score).
//  pr (query positions) hoisted to registers (loop-invariant; R9 re-read
//  them from LDS every iter because the clobber fences blocked hoisting).
//  Zero in-loop vmem except prefetch; 1 barrier/iter; K/V/pqk dbuf.
//  Discriminator: per-CU LDS read volume ~= R9's. If dur ~=R9 -> LDS-BW
//  bound -> pivot to 32x32 MFMA (2x fewer LDS bytes/FLOP) next.
// ---------------------------------------------------------------------------
__global__ __launch_bounds__(256, 2) void attn_kernel(
    const u16* __restrict__ Qb, const u16* __restrict__ Kb,
    const u16* __restrict__ Vt, const float* __restrict__ pq,
    u16* __restrict__ Op, float* __restrict__ ml) {
  __shared__ u16 kbuf[2][BN * 256];     // 16 KB x2
  __shared__ u16 vbuf[2][256 * BN];     // 16 KB x2 (full features)
  __shared__ u16 pbuf[4][16 * 36];      // per-wave P (1.1 KB each)
  __shared__ float pqk[2][BN * 4];      // key-side pq, dbuf (1 KB)

  const int tid = threadIdx.x;
  const int lane = tid & 63;
  const int wave = tid >> 6;
  const int l15 = lane & 15;
  const int q4 = lane >> 4;
  const int rb = blockIdx.x;
  const int sp = blockIdx.y;
  const int q0 = rb * 64;
  const int wrow = wave * 16;

#define STAGE(T)                                                              \
  do {                                                                        \
    const int key0_ = sp * SPLEN + (T) * BN;                                  \
    const int b_ = (T) & 1;                                                   \
    if (wave < 2) {                                                           \
      const int rb0 = wave * 16;                                              \
      _Pragma("unroll")                                                       \
      for (int i = 0; i < 8; ++i) {                                           \
        int r = rb0 + i * 2 + (lane >> 5);                                    \
        int c = (lane & 31) ^ (r & 7);                                        \
        async16(Kb + (size_t)(key0_ + r) * 256 + c * 8,                       \
                &kbuf[b_][(rb0 + i * 2) * 256]);                              \
      }                                                                       \
    } else {                                                                  \
      const int fb0 = (wave - 2) * 128;                                       \
      _Pragma("unroll")                                                       \
      for (int i = 0; i < 8; ++i) {                                           \
        int f = fb0 + i * 16 + (lane >> 2);                                   \
        int c = (lane & 3) ^ (f & 3);                                         \
        async16(Vt + (size_t)f * NTOK + key0_ + c * 8,                        \
                &vbuf[b_][(fb0 + i * 16) * 32]);                              \
      }                                                                       \
      if (wave == 3 && lane < 32)                                             \
        async16(((const f32x4*)pq) + key0_ + lane, &pqk[b_][0]);              \
    }                                                                         \
  } while (0)

  // ---- persistent registers: Q fragments (32 regs) + query positions ----
  bf16x8 qa[8];
#pragma unroll
  for (int kc = 0; kc < 8; ++kc)
    qa[kc] = *(const bf16x8*)(Qb + (size_t)(q0 + wrow + l15) * 256 +
                              kc * 32 + q4 * 8);
  f32x4 pr[4];
#pragma unroll
  for (int r = 0; r < 4; ++r)
    pr[r] = ((const f32x4*)pq)[q0 + wrow + q4 * 4 + r];

  f32x4 O[16];
#pragma unroll
  for (int ft = 0; ft < 16; ++ft) O[ft] = (f32x4){0.f, 0.f, 0.f, 0.f};
  float lrow[4] = {0.f, 0.f, 0.f, 0.f};

  STAGE(0);

#pragma unroll 1
  for (int it = 0; it < ITERS; ++it) {
    const int cur = it & 1;
    asm volatile("s_waitcnt vmcnt(0)" ::: "memory");
    __syncthreads();

    // prefetch tile it+1 (last iter: benign identical rewrite)
    const int nx = (it + 1 < ITERS) ? (it + 1) : (ITERS - 1);
    STAGE(nx);

    // ---- S = Q K^T (16 rows x 32 keys, computed exactly once) ----
    f32x4 S[2];
#pragma unroll
    for (int nt = 0; nt < 2; ++nt) S[nt] = (f32x4){0.f, 0.f, 0.f, 0.f};
#pragma unroll
    for (int kc = 0; kc < 8; ++kc) {
#pragma unroll
      for (int nt = 0; nt < 2; ++nt) {
        bf16x8 kf = *(const bf16x8*)(&kbuf[cur][(nt * 16 + l15) * 256 +
                                     (((kc * 4 + q4) ^ (l15 & 7)) * 8)]);
        S[nt] = mfma16(qa[kc], kf, S[nt]);
      }
    }

    // ---- decay + exp (fixed reference; x in [-4,4] by construction) ----
    {
      f32x4 pk[2];
#pragma unroll
      for (int nt = 0; nt < 2; ++nt)
        pk[nt] = ((const f32x4*)pqk[cur])[nt * 16 + l15];
#pragma unroll
      for (int r = 0; r < 4; ++r) {
        float lacc = 0.f;
#pragma unroll
        for (int nt = 0; nt < 2; ++nt) {
          float h = pr[r][3] + pk[nt][3];
          h = fmaf(-pr[r][0], pk[nt][0], h);
          h = fmaf(-pr[r][1], pk[nt][1], h);
          h = fmaf(-pr[r][2], pk[nt][2], h);
          h = fmaxf(h, 0.f);
          float dec = exp2_hw(fmaf(h, -LOG2E, DECC));
          float p = exp2_hw(S[nt][r] * dec);
          S[nt][r] = p;
          lacc += p;
        }
        lrow[r] += lacc;
      }
    }

    // ---- P tile (bf16) into per-wave pbuf ----
    asm volatile("" ::: "memory");
#pragma unroll
    for (int nt = 0; nt < 2; ++nt)
#pragma unroll
      for (int r = 0; r < 4; ++r)
        pbuf[wave][(q4 * 4 + r) * 36 + nt * 16 + l15] = f2bf(S[nt][r]);
    asm volatile("s_waitcnt lgkmcnt(0)" ::: "memory");
    asm volatile("" ::: "memory");

    // ---- O += P V (full 256 features) ----
    {
      PB pb;
      const u16* pp = &pbuf[wave][l15 * 36 + q4 * 8];
      pb.d[0] = *(const uint64_t*)(pp);
      pb.d[1] = *(const uint64_t*)(pp + 4);
      bf16x8 pa = pb.v;
#pragma unroll
      for (int ft = 0; ft < 16; ++ft) {
        bf16x8 vf = *(const bf16x8*)(&vbuf[cur][(ft * 16 + l15) * 32 +
                                     ((q4 ^ (l15 & 3)) * 8)]);
        O[ft] = mfma16(pa, vf, O[ft]);
      }
    }
  }

  // ---- epilogue ----
#pragma unroll
  for (int r = 0; r < 4; ++r) lrow[r] = rowsum16(lrow[r]);

#pragma unroll
  for (int ft = 0; ft < 16; ++ft)
#pragma unroll
    for (int r = 0; r < 4; ++r) {
      int row = q0 + wrow + q4 * 4 + r;
      Op[((size_t)sp * NTOK + row) * 256 + ft * 16 + l15] = f2bf(O[ft][r]);
    }
  if (l15 == 0) {
#pragma unroll
    for (int r = 0; r < 4; ++r) {
      int row = q0 + wrow + q4 * 4 + r;
      ml[sp * NTOK + row] = lrow[r];
    }
  }
#undef STAGE
}

// ---------------------------------------------------------------------------
// Kernel 3: combine splits: H = (sum O_s) / (1 + sum l_s) + residual.
// ---------------------------------------------------------------------------
__global__ __launch_bounds__(256) void combine_kernel(
    const float* __restrict__ X, const u16* __restrict__ Op,
    const float* __restrict__ ml, float* __restrict__ out) {
  const int row = blockIdx.x;
  const int f = threadIdx.x;
  float den = 1.f, num = 0.f;
#pragma unroll
  for (int s = 0; s < KSPLIT; ++s) {
    den += ml[s * NTOK + row];
    num += bf2f(Op[((size_t)s * NTOK + row) * 256 + f]);
  }
  out[(size_t)row * 256 + f] = num / den + X[(size_t)row * XSTRIDE + f];
}

// ---------------------------------------------------------------------------
extern "C" void kernel_launch(void* const* d_in, const int* in_sizes, int n_in,
                              void* d_out, int out_size, void* d_ws, size_t ws_size,
                              hipStream_t stream) {
  (void)in_sizes; (void)n_in; (void)out_size; (void)ws_size;
  const float* X  = (const float*)d_in[0];
  const float* WQ = (const float*)d_in[1];
  const float* bQ = (const float*)d_in[2];
  const float* WK = (const float*)d_in[3];
  const float* bK = (const float*)d_in[4];
  const float* WV = (const float*)d_in[5];
  const float* bV = (const float*)d_in[6];
  float* out = (float*)d_out;
  char* ws = (char*)d_ws;

  // ws: Qb 4M | Kb 4M | Vt 4M | pq 128K | Wt 384K | Op 16M | ml 128K
  u16*   Qb = (u16*)(ws);
  u16*   Kb = (u16*)(ws + ((size_t)4 << 20));
  u16*   Vt = (u16*)(ws + ((size_t)8 << 20));
  float* pq = (float*)(ws + ((size_t)12 << 20));
  u16*   Wt = (u16*)(ws + ((size_t)12 << 20) + 131072);
  u16*   Op = (u16*)(ws + ((size_t)12 << 20) + 131072 + 393216);
  float* ml = (float*)(ws + ((size_t)12 << 20) + 131072 + 393216 +
                       (size_t)KSPLIT * NTOK * 256 * 2);

  pq_kernel<<<dim3(NTOK / 256), dim3(256), 0, stream>>>(X, pq);
  wprep_kernel<<<dim3(768), dim3(256), 0, stream>>>(WQ, WK, WV, Wt);
  qkv_kernel<<<dim3(64, 12), dim3(256), 0, stream>>>(X, Wt, bQ, bK, bV,
                                                     Qb, Kb, Vt);
  attn_kernel<<<dim3(128, KSPLIT), dim3(256), 0, stream>>>(Qb, Kb, Vt, pq,
                                                           Op, ml);
  combine_kernel<<<dim3(NTOK), dim3(256), 0, stream>>>(X, Op, ml, out);
}